// Round 11
// baseline (310.100 us; speedup 1.0000x reference)
//
#include <hip/hip_runtime.h>
#include <math.h>

#define N_NODES 100000
#define N_EDGES 1600000
#define IN_C    128
#define HID     256
#define KEIG    64
#define OUT_C   16

#define NPB      256
#define NBUCKET  ((N_NODES + NPB - 1) / NPB)             // 391
#define EDGE_TILE 4096
#define NTILE    ((N_EDGES + EDGE_TILE - 1) / EDGE_TILE) // 391
#define CAP      8960                                    // padded bucket cap (LDS stage)

#define TRANS_BLOCKS   ((N_NODES + 63) / 64)             // 1563
#define GATHER_BLOCKS  2048
#define CUT_BLOCKS     2048
#define SSP_BLOCKS     512
#define OUT_BLOCKS     ((N_NODES + 255) / 256)           // 391
#define TAIL_BLOCKS    (CUT_BLOCKS + SSP_BLOCKS + OUT_BLOCKS)

typedef __attribute__((ext_vector_type(8))) short short8;
typedef __attribute__((ext_vector_type(4))) float f32x4;

__device__ __forceinline__ float wave_sum(float v) {
#pragma unroll
    for (int m = 32; m; m >>= 1) v += __shfl_xor(v, m, 64);
    return v;
}
__device__ __forceinline__ float wave_max(float v) {
#pragma unroll
    for (int m = 32; m; m >>= 1) v = fmaxf(v, __shfl_xor(v, m, 64));
    return v;
}
__device__ __forceinline__ float bf2f(unsigned int u) {
    return __uint_as_float((u & 0xffffu) << 16);
}
__device__ __forceinline__ unsigned short f2bf(float f) {
    unsigned int u = __float_as_uint(f);
    u += 0x7fff + ((u >> 16) & 1);
    return (unsigned short)(u >> 16);
}
__device__ __forceinline__ float fp8tof(int b) {
    return __builtin_amdgcn_cvt_f32_fp8(b, 0);
}
__device__ __forceinline__ unsigned char f2fp8(float f) {
    int p = __builtin_amdgcn_cvt_pk_fp8_f32(f, f, 0, false);
    return (unsigned char)(p & 0xff);
}

#define FMA4(P, s, W) \
    P.x = fmaf(s, W.x, P.x); P.y = fmaf(s, W.y, P.y); \
    P.z = fmaf(s, W.z, P.z); P.w = fmaf(s, W.w, P.w);

// 16 fp8 row-gathers, indices from uniform (scalar) CSR reads
#define GATHER16(TBL, DST) do {                                               \
    int r0 = csr_row[ps + j + 0],  r1 = csr_row[ps + j + 1];                  \
    int r2 = csr_row[ps + j + 2],  r3 = csr_row[ps + j + 3];                  \
    int r4 = csr_row[ps + j + 4],  r5 = csr_row[ps + j + 5];                  \
    int r6 = csr_row[ps + j + 6],  r7 = csr_row[ps + j + 7];                  \
    int r8 = csr_row[ps + j + 8],  r9 = csr_row[ps + j + 9];                  \
    int rA = csr_row[ps + j + 10], rB = csr_row[ps + j + 11];                 \
    int rC = csr_row[ps + j + 12], rD = csr_row[ps + j + 13];                 \
    int rE = csr_row[ps + j + 14], rF = csr_row[ps + j + 15];                 \
    int b0 = TBL[(unsigned)r0 * 64u + lane], b1 = TBL[(unsigned)r1 * 64u + lane]; \
    int b2 = TBL[(unsigned)r2 * 64u + lane], b3 = TBL[(unsigned)r3 * 64u + lane]; \
    int b4 = TBL[(unsigned)r4 * 64u + lane], b5 = TBL[(unsigned)r5 * 64u + lane]; \
    int b6 = TBL[(unsigned)r6 * 64u + lane], b7 = TBL[(unsigned)r7 * 64u + lane]; \
    int b8 = TBL[(unsigned)r8 * 64u + lane], b9 = TBL[(unsigned)r9 * 64u + lane]; \
    int bA = TBL[(unsigned)rA * 64u + lane], bB = TBL[(unsigned)rB * 64u + lane]; \
    int bC = TBL[(unsigned)rC * 64u + lane], bD = TBL[(unsigned)rD * 64u + lane]; \
    int bE = TBL[(unsigned)rE * 64u + lane], bF = TBL[(unsigned)rF * 64u + lane]; \
    DST += (((fp8tof(b0) + fp8tof(b1)) + (fp8tof(b2) + fp8tof(b3)))           \
          + ((fp8tof(b4) + fp8tof(b5)) + (fp8tof(b6) + fp8tof(b7))))          \
         + (((fp8tof(b8) + fp8tof(b9)) + (fp8tof(bA) + fp8tof(bB)))           \
          + ((fp8tof(bC) + fp8tof(bD)) + (fp8tof(bE) + fp8tof(bF))));         \
} while (0)

// ---------------- small precompute (+ zero bucket counts, pad rows, gpad) --------
__global__ void prep_weff(const float* __restrict__ mlpxW, const float* __restrict__ mlpxb,
                          const float* __restrict__ finW, const float* __restrict__ finb,
                          float* __restrict__ Weff, float* __restrict__ beff,
                          int* __restrict__ bcnt, unsigned char* __restrict__ WT8,
                          unsigned char* __restrict__ S8, int* __restrict__ gpad) {
    int t = blockIdx.x * blockDim.x + threadIdx.x;
    const int NW = (IN_C + KEIG) * OUT_C;
    if (t < NW) {
        int k = t >> 4, o = t & 15;
        float acc;
        if (k < IN_C) {
            acc = 0.f;
            for (int c = 0; c < HID; ++c)
                acc += mlpxW[c * IN_C + k] * finW[o * (HID + KEIG) + c];
        } else {
            acc = finW[o * (HID + KEIG) + HID + (k - IN_C)];
        }
        Weff[k * OUT_C + o] = acc;
    }
    int tb = t - NW;
    if (tb >= 0 && tb < OUT_C) {
        float acc = finb[tb];
        for (int c = 0; c < HID; ++c) acc += mlpxb[c] * finW[tb * (HID + KEIG) + c];
        beff[tb] = acc;
    }
    int tz = t - (NW + OUT_C);
    if (tz >= 0 && tz <= NBUCKET) bcnt[tz] = 0;
    int tp = t - (NW + OUT_C + NBUCKET + 1);
    if (tp >= 0 && tp < 16) {   // zero sentinel rows (64 B each) as 16 ints
        ((int*)(WT8 + (size_t)N_NODES * 64))[tp] = 0;
        ((int*)(S8 + (size_t)N_NODES * 64))[tp] = 0;
        if (tp == 0) *gpad = 0;
    }
}

// ---------------- fused: transpose_w (blocks < TRANS_BLOCKS) | bucket_hist -------
__global__ __launch_bounds__(256) void fused_prep(const float* __restrict__ W,
                                                  unsigned char* __restrict__ WT8,
                                                  const int* __restrict__ ei,
                                                  int* __restrict__ bcnt) {
    __shared__ __align__(16) char sm[64 * 65 * 4];
    int t = threadIdx.x;
    if (blockIdx.x < TRANS_BLOCKS) {
        float (*tile)[65] = (float (*)[65])sm;
        int n0 = blockIdx.x * 64;
        int tn = t & 63, tq = t >> 6;
#pragma unroll
        for (int kk = 0; kk < 16; ++kk) {
            int k = tq * 16 + kk;
            int n = n0 + tn;
            tile[k][tn] = (n < N_NODES) ? W[(long long)k * N_NODES + n] : 0.f;
        }
        __syncthreads();
        int tk = t & 63;
#pragma unroll
        for (int ii = 0; ii < 16; ++ii) {
            int n = n0 + tq * 16 + ii;
            if (n < N_NODES) WT8[(unsigned)n * 64u + tk] = f2fp8(tile[tk][tq * 16 + ii] * 32.f);
        }
    } else {
        int* h = (int*)sm;
        for (int i = t; i < NBUCKET; i += 256) h[i] = 0;
        __syncthreads();
        int tile_i = blockIdx.x - TRANS_BLOCKS;
        int e0 = tile_i * EDGE_TILE;
        int e1 = min(e0 + EDGE_TILE, N_EDGES);
        for (int e = e0 + t; e < e1; e += 256)
            atomicAdd(&h[ei[N_EDGES + e] >> 8], 1);
        __syncthreads();
        for (int i = t; i < NBUCKET; i += 256)
            if (h[i]) atomicAdd(&bcnt[i], h[i]);
    }
}

__global__ void bucket_scan(const int* __restrict__ bcnt, int* __restrict__ bbase,
                            int* __restrict__ bcur) {
    __shared__ int sh[512];
    int t = threadIdx.x;
    int v = (t < NBUCKET) ? bcnt[t] : 0;
    sh[t] = v;
    __syncthreads();
    for (int d = 1; d < 512; d <<= 1) {
        int u = (t >= d) ? sh[t - d] : 0;
        __syncthreads();
        sh[t] += u;
        __syncthreads();
    }
    if (t < NBUCKET) { bbase[t] = sh[t] - v; bcur[t] = sh[t] - v; }
    if (t == 0) bbase[NBUCKET] = N_EDGES;
}

// partition edges into bucket regions via LDS staging (coalesced ebuf writes)
__global__ void bucket_scatter(const int* __restrict__ ei, int* __restrict__ bcur,
                               int* __restrict__ ebuf) {
    __shared__ int h[NBUCKET];
    __shared__ int gb[NBUCKET];
    __shared__ int lpre[NBUCKET];
    __shared__ int psum[256];
    __shared__ int stage[EDGE_TILE];
    __shared__ short bkt[EDGE_TILE];
    int t = threadIdx.x;
    for (int i = t; i < NBUCKET; i += 256) h[i] = 0;
    __syncthreads();
    int e0 = blockIdx.x * EDGE_TILE;
    int e1 = min(e0 + EDGE_TILE, N_EDGES);
    int nt = e1 - e0;
    for (int e = e0 + t; e < e1; e += 256)
        atomicAdd(&h[ei[N_EDGES + e] >> 8], 1);
    __syncthreads();
    int a0 = (2 * t < NBUCKET) ? h[2 * t] : 0;
    int a1 = (2 * t + 1 < NBUCKET) ? h[2 * t + 1] : 0;
    psum[t] = a0 + a1;
    __syncthreads();
    for (int d = 1; d < 256; d <<= 1) {
        int u = (t >= d) ? psum[t - d] : 0;
        __syncthreads();
        psum[t] += u;
        __syncthreads();
    }
    int base = (t == 0) ? 0 : psum[t - 1];
    if (2 * t < NBUCKET) lpre[2 * t] = base;
    if (2 * t + 1 < NBUCKET) lpre[2 * t + 1] = base + a0;
    __syncthreads();
    for (int i = t; i < NBUCKET; i += 256) {
        int c = h[i];
        gb[i] = c ? atomicAdd(&bcur[i], c) : 0;
        h[i] = lpre[i];
    }
    __syncthreads();
    for (int e = e0 + t; e < e1; e += 256) {
        int r = ei[e];
        int c = ei[N_EDGES + e];
        int b = c >> 8;
        int slot = atomicAdd(&h[b], 1);
        stage[slot] = r | ((c & 255) << 17);
        bkt[slot] = (short)b;
    }
    __syncthreads();
    for (int s = t; s < nt; s += 256) {
        int b = bkt[s];
        ebuf[gb[b] + s - lpre[b]] = stage[s];
    }
}

// one block per bucket: deg->offsets, padded CSR (multiple of 16, sentinel N_NODES)
__global__ void csr_build(const int* __restrict__ ebuf, const int* __restrict__ bbase,
                          int* __restrict__ offsets, int* __restrict__ pstart,
                          int* __restrict__ csr_row, int* __restrict__ gpad) {
    __shared__ int hist[NPB];
    __shared__ int sh[NPB];
    __shared__ int curs[NPB];
    __shared__ int staged[CAP];
    __shared__ int pbase_sh;
    int b = blockIdx.x;
    int t = threadIdx.x;
    int s0 = bbase[b], s1 = bbase[b + 1];
    hist[t] = 0;
    __syncthreads();
    for (int i = s0 + t; i < s1; i += 256)
        atomicAdd(&hist[ebuf[i] >> 17], 1);
    __syncthreads();
    int v = hist[t];
    int pv = (v + 15) & ~15;
    sh[t] = pv;
    __syncthreads();
    for (int d = 1; d < 256; d <<= 1) {
        int u = (t >= d) ? sh[t - d] : 0;
        __syncthreads();
        sh[t] += u;
        __syncthreads();
    }
    int pexcl = sh[t] - pv;
    int pt = sh[255];
    if (t == 0) pbase_sh = atomicAdd(gpad, pt);
    __syncthreads();
    int pbase = pbase_sh;
    int node = b * NPB + t;
    if (node < N_NODES) { offsets[node] = v; pstart[node] = pbase + pexcl; }
    curs[t] = pexcl;
    __syncthreads();
    if (pt <= CAP) {
        for (int i = t; i < pt; i += 256) staged[i] = N_NODES;
        __syncthreads();
        for (int i = s0 + t; i < s1; i += 256) {
            int pk = ebuf[i];
            int pos = atomicAdd(&curs[pk >> 17], 1);
            staged[pos] = pk & 0x1FFFF;
        }
        __syncthreads();
        for (int i = t; i < pt; i += 256) csr_row[pbase + i] = staged[i];
    } else {
        for (int i = t; i < pt; i += 256) csr_row[pbase + i] = N_NODES;
        __syncthreads();
        for (int i = s0 + t; i < s1; i += 256) {
            int pk = ebuf[i];
            int pos = atomicAdd(&curs[pk >> 17], 1);
            csr_row[pbase + pos] = pk & 0x1FFFF;
        }
    }
}

// ---------------- pass 1: padded 16-wide fp8 gather + softmax + deg_term ---------
__global__ void gather_softmax(const int* __restrict__ offsets, const int* __restrict__ pstart,
                               const int* __restrict__ csr_row,
                               const unsigned char* __restrict__ WT8,
                               const float* __restrict__ MLPb,
                               unsigned short* __restrict__ Sb,
                               unsigned char* __restrict__ S8,
                               float* __restrict__ dtp) {
    int lane = threadIdx.x & 63;
    int wib = __builtin_amdgcn_readfirstlane(threadIdx.x >> 6);
    int gw = blockIdx.x * 4 + wib;
    int nw = gridDim.x * 4;
    float bias = MLPb[lane];
    float dacc = 0.f;
    for (int n = gw; n < N_NODES; n += nw) {
        int deg = __builtin_amdgcn_readfirstlane(offsets[n]);
        int ps  = __builtin_amdgcn_readfirstlane(pstart[n]);
        int plen = (deg + 15) & ~15;
        float acc = 0.f;
        for (int j = 0; j < plen; j += 16) GATHER16(WT8, acc);
        acc = bias + acc * 0.03125f;
        float m = wave_max(acc);
        float e = __expf(acc - m);
        float sm = wave_sum(e);
        float sv = e / sm;
        unsigned idx = (unsigned)n * 64u + lane;
        Sb[idx] = f2bf(sv);
        S8[idx] = f2fp8(sv * 64.f);
        dacc += (float)deg * sv * sv;
    }
    dacc = wave_sum(dacc);
    __shared__ float red[4];
    if (lane == 0) red[wib] = dacc;
    __syncthreads();
    if (threadIdx.x == 0) dtp[blockIdx.x] = red[0] + red[1] + red[2] + red[3];
}

// ---------------- fused tail: cut | ss_mfma | out ----------------
__global__ __launch_bounds__(256) void fused_tail(
        const int* __restrict__ offsets, const int* __restrict__ pstart,
        const int* __restrict__ csr_row,
        const unsigned short* __restrict__ Sb, const unsigned char* __restrict__ S8,
        float* __restrict__ cutp, float* __restrict__ ssp,
        const float* __restrict__ x, const float* __restrict__ Weff,
        const float* __restrict__ beff, float* __restrict__ out) {
    __shared__ __align__(16) char sm[768 * 16 + 64];
    int t = threadIdx.x;
    int bid = blockIdx.x;

    if (bid < CUT_BLOCKS) {
        // ---- cut ----
        int lane = t & 63;
        int wib = __builtin_amdgcn_readfirstlane(t >> 6);
        int gw = bid * 4 + wib;
        int nw = CUT_BLOCKS * 4;
        float acc = 0.f;
        for (int n = gw; n < N_NODES; n += nw) {
            float sc = bf2f(Sb[(unsigned)n * 64u + lane]);
            int deg = __builtin_amdgcn_readfirstlane(offsets[n]);
            int ps  = __builtin_amdgcn_readfirstlane(pstart[n]);
            int plen = (deg + 15) & ~15;
            float g = 0.f;
            for (int j = 0; j < plen; j += 16) GATHER16(S8, g);
            acc += sc * g * 0.015625f;
        }
        acc = wave_sum(acc);
        float* red = (float*)sm;
        if (lane == 0) red[wib] = acc;
        __syncthreads();
        if (t == 0) cutp[bid] = red[0] + red[1] + red[2] + red[3];
    } else if (bid < CUT_BLOCKS + SSP_BLOCKS) {
        // ---- SS = S^T S via MFMA ----
        int bid2 = bid - CUT_BLOCKS;
        unsigned short (*Sr)[66] = (unsigned short (*)[66])sm;
        int lane = t & 63;
        int w = t >> 6;
        int m = lane & 15;
        int quad = lane >> 4;
        int srow = t >> 3;
        int spart = t & 7;
        f32x4 a0 = {0.f,0.f,0.f,0.f}, a1 = {0.f,0.f,0.f,0.f};
        f32x4 a2 = {0.f,0.f,0.f,0.f}, a3 = {0.f,0.f,0.f,0.f};
        for (int base = bid2 * 32; base < N_NODES; base += SSP_BLOCKS * 32) {
            const uint4* g = (const uint4*)(Sb + (long long)(base + srow) * 64 + spart * 8);
            uint4 d = *g;
            __syncthreads();
            unsigned int* rowp = (unsigned int*)&Sr[srow][0];
            rowp[spart * 4 + 0] = d.x;
            rowp[spart * 4 + 1] = d.y;
            rowp[spart * 4 + 2] = d.z;
            rowp[spart * 4 + 3] = d.w;
            __syncthreads();
            short8 f0, f1, f2, f3;
#pragma unroll
            for (int j = 0; j < 8; ++j) {
                int k = quad * 8 + j;
                f0[j] = (short)Sr[k][m];
                f1[j] = (short)Sr[k][16 + m];
                f2[j] = (short)Sr[k][32 + m];
                f3[j] = (short)Sr[k][48 + m];
            }
            short8 fa = (w == 0) ? f0 : (w == 1) ? f1 : (w == 2) ? f2 : f3;
            a0 = __builtin_amdgcn_mfma_f32_16x16x32_bf16(fa, f0, a0, 0, 0, 0);
            a1 = __builtin_amdgcn_mfma_f32_16x16x32_bf16(fa, f1, a1, 0, 0, 0);
            a2 = __builtin_amdgcn_mfma_f32_16x16x32_bf16(fa, f2, a2, 0, 0, 0);
            a3 = __builtin_amdgcn_mfma_f32_16x16x32_bf16(fa, f3, a3, 0, 0, 0);
        }
        float* dst = ssp + (size_t)bid2 * 4096;
#pragma unroll
        for (int r = 0; r < 4; ++r) {
            int row = w * 16 + quad * 4 + r;
            dst[row * 64 +  0 + m] = a0[r];
            dst[row * 64 + 16 + m] = a1[r];
            dst[row * 64 + 32 + m] = a2[r];
            dst[row * 64 + 48 + m] = a3[r];
        }
    } else {
        // ---- out: logits + log_softmax ----
        float4* Wsh = (float4*)sm;
        float* bsh = (float*)(sm + 768 * 16);
        const float4* W4 = (const float4*)Weff;
        for (int i = t; i < 768; i += 256) Wsh[i] = W4[i];
        if (t < 16) bsh[t] = beff[t];
        __syncthreads();
        int r = (bid - CUT_BLOCKS - SSP_BLOCKS) * 256 + t;
        if (r >= N_NODES) return;
        float4 p0 = make_float4(bsh[0], bsh[1], bsh[2], bsh[3]);
        float4 p1 = make_float4(bsh[4], bsh[5], bsh[6], bsh[7]);
        float4 p2 = make_float4(bsh[8], bsh[9], bsh[10], bsh[11]);
        float4 p3 = make_float4(bsh[12], bsh[13], bsh[14], bsh[15]);
        const float4* xr = (const float4*)(x + (long long)r * IN_C);
#pragma unroll 8
        for (int j = 0; j < 32; ++j) {
            float4 xv = xr[j];
            int k = j * 4;
            float xs[4] = {xv.x, xv.y, xv.z, xv.w};
#pragma unroll
            for (int c = 0; c < 4; ++c) {
                float s = xs[c];
                float4 w0 = Wsh[(k + c) * 4 + 0];
                float4 w1 = Wsh[(k + c) * 4 + 1];
                float4 w2 = Wsh[(k + c) * 4 + 2];
                float4 w3 = Wsh[(k + c) * 4 + 3];
                FMA4(p0, s, w0); FMA4(p1, s, w1); FMA4(p2, s, w2); FMA4(p3, s, w3);
            }
        }
        const uint2* sr = (const uint2*)(Sb + (long long)r * 64);
#pragma unroll 8
        for (int j = 0; j < 16; ++j) {
            uint2 u = sr[j];
            float xs[4] = {bf2f(u.x), bf2f(u.x >> 16), bf2f(u.y), bf2f(u.y >> 16)};
            int k = IN_C + j * 4;
#pragma unroll
            for (int c = 0; c < 4; ++c) {
                float s = xs[c];
                float4 w0 = Wsh[(k + c) * 4 + 0];
                float4 w1 = Wsh[(k + c) * 4 + 1];
                float4 w2 = Wsh[(k + c) * 4 + 2];
                float4 w3 = Wsh[(k + c) * 4 + 3];
                FMA4(p0, s, w0); FMA4(p1, s, w1); FMA4(p2, s, w2); FMA4(p3, s, w3);
            }
        }
        float m = fmaxf(fmaxf(fmaxf(p0.x, p0.y), fmaxf(p0.z, p0.w)),
                        fmaxf(fmaxf(fmaxf(p1.x, p1.y), fmaxf(p1.z, p1.w)),
                              fmaxf(fmaxf(fmaxf(p2.x, p2.y), fmaxf(p2.z, p2.w)),
                                    fmaxf(fmaxf(p3.x, p3.y), fmaxf(p3.z, p3.w)))));
        float sum = __expf(p0.x - m) + __expf(p0.y - m) + __expf(p0.z - m) + __expf(p0.w - m)
                  + __expf(p1.x - m) + __expf(p1.y - m) + __expf(p1.z - m) + __expf(p1.w - m)
                  + __expf(p2.x - m) + __expf(p2.y - m) + __expf(p2.z - m) + __expf(p2.w - m)
                  + __expf(p3.x - m) + __expf(p3.y - m) + __expf(p3.z - m) + __expf(p3.w - m);
        float lse = m + logf(sum);
        float4* o4 = (float4*)(out + (long long)r * OUT_C);
        o4[0] = make_float4(p0.x - lse, p0.y - lse, p0.z - lse, p0.w - lse);
        o4[1] = make_float4(p1.x - lse, p1.y - lse, p1.z - lse, p1.w - lse);
        o4[2] = make_float4(p2.x - lse, p2.y - lse, p2.z - lse, p2.w - lse);
        o4[3] = make_float4(p3.x - lse, p3.y - lse, p3.z - lse, p3.w - lse);
    }
}

__global__ void reduce_ss(const float* __restrict__ ssp, float* __restrict__ SS) {
    int e = blockIdx.x * blockDim.x + threadIdx.x;
    float s = 0.f;
    for (int p = 0; p < SSP_BLOCKS; ++p) s += ssp[(size_t)p * 4096 + e];
    SS[e] = s;
}

// ---------------- scalar losses ----------------
__global__ void scalars_kernel(const float* __restrict__ cutp, const float* __restrict__ dtp,
                               const float* __restrict__ SS, float* __restrict__ out) {
    __shared__ float red[256];
    int t = threadIdx.x;
    float c = 0.f;
    for (int i = t; i < CUT_BLOCKS; i += 256) c += cutp[i];
    red[t] = c; __syncthreads();
    for (int s = 128; s; s >>= 1) { if (t < s) red[t] += red[t + s]; __syncthreads(); }
    float cut = red[0]; __syncthreads();

    float d = 0.f;
    for (int i = t; i < GATHER_BLOCKS; i += 256) d += dtp[i];
    red[t] = d; __syncthreads();
    for (int s = 128; s; s >>= 1) { if (t < s) red[t] += red[t + s]; __syncthreads(); }
    float dterm = red[0]; __syncthreads();

    float ss[16];
    float sq = 0.f;
#pragma unroll
    for (int j = 0; j < 16; ++j) { ss[j] = SS[t * 16 + j]; sq += ss[j] * ss[j]; }
    red[t] = sq; __syncthreads();
    for (int s = 128; s; s >>= 1) { if (t < s) red[t] += red[t + s]; __syncthreads(); }
    float nrm = sqrtf(red[0]); __syncthreads();

    float osq = 0.f;
#pragma unroll
    for (int j = 0; j < 16; ++j) {
        int idx = t * 16 + j;
        float v = ss[j] / nrm - ((idx % 65 == 0) ? 0.125f : 0.f);
        osq += v * v;
    }
    red[t] = osq; __syncthreads();
    for (int s = 128; s; s >>= 1) { if (t < s) red[t] += red[t + s]; __syncthreads(); }
    if (t == 0) {
        float loss = -(cut / dterm) + sqrtf(red[0]);
        out[(long long)N_NODES * OUT_C] = loss;
    }
}

extern "C" void kernel_launch(void* const* d_in, const int* in_sizes, int n_in,
                              void* d_out, int out_size, void* d_ws, size_t ws_size,
                              hipStream_t stream) {
    const float* x     = (const float*)d_in[0];
    const int*   ei    = (const int*)d_in[1];
    const float* MLPW  = (const float*)d_in[2];
    const float* MLPb  = (const float*)d_in[3];
    const float* mlpxW = (const float*)d_in[4];
    const float* mlpxb = (const float*)d_in[5];
    const float* finW  = (const float*)d_in[6];
    const float* finb  = (const float*)d_in[7];
    float* out = (float*)d_out;
    char* ws = (char*)d_ws;

    unsigned char*  WT8 = (unsigned char*)ws;                                 // (N+1)*64
    unsigned char*  S8  = (unsigned char*)(ws + (size_t)(N_NODES + 1) * 64);  // (N+1)*64
    unsigned short* Sb  = (unsigned short*)(ws + (size_t)(N_NODES + 1) * 128);// N*64*2
    char* p = ws + (size_t)(N_NODES + 1) * 128 + (size_t)N_NODES * 128;
    float* ssp  = (float*)p;                                 // 512*4096 f
    float* SS   = ssp + (size_t)SSP_BLOCKS * 4096;           // 4096
    float* Weff = SS + 4096;                                 // 3072
    float* beff = Weff + 192 * 16;                           // 16
    float* cutp = beff + 16;                                 // CUT_BLOCKS
    float* dtp  = cutp + CUT_BLOCKS;                         // GATHER_BLOCKS
    int* ebuf    = (int*)(dtp + GATHER_BLOCKS);              // E
    int* csr_row = ebuf + N_EDGES;                           // E + 16N (padded)
    int* offsets = csr_row + N_EDGES + 16 * N_NODES;         // N+1
    int* pstart  = offsets + N_NODES + 1;                    // N
    int* bcnt    = pstart + N_NODES;                         // NBUCKET+1
    int* bbase   = bcnt + NBUCKET + 1;                       // NBUCKET+1
    int* bcur    = bbase + NBUCKET + 1;                      // NBUCKET
    int* gpad    = bcur + NBUCKET;                           // 1

    hipLaunchKernelGGL(prep_weff, dim3(16), dim3(256), 0, stream,
                       mlpxW, mlpxb, finW, finb, Weff, beff, bcnt, WT8, S8, gpad);
    hipLaunchKernelGGL(fused_prep, dim3(TRANS_BLOCKS + NTILE), dim3(256), 0, stream,
                       MLPW, WT8, ei, bcnt);
    hipLaunchKernelGGL(bucket_scan, dim3(1), dim3(512), 0, stream, bcnt, bbase, bcur);
    hipLaunchKernelGGL(bucket_scatter, dim3(NTILE), dim3(256), 0, stream, ei, bcur, ebuf);
    hipLaunchKernelGGL(csr_build, dim3(NBUCKET), dim3(256), 0, stream,
                       ebuf, bbase, offsets, pstart, csr_row, gpad);
    hipLaunchKernelGGL(gather_softmax, dim3(GATHER_BLOCKS), dim3(256), 0, stream,
                       offsets, pstart, csr_row, WT8, MLPb, Sb, S8, dtp);
    hipLaunchKernelGGL(fused_tail, dim3(TAIL_BLOCKS), dim3(256), 0, stream,
                       offsets, pstart, csr_row, Sb, S8, cutp, ssp, x, Weff, beff, out);
    hipLaunchKernelGGL(reduce_ss, dim3(16), dim3(256), 0, stream, ssp, SS);
    hipLaunchKernelGGL(scalars_kernel, dim3(1), dim3(256), 0, stream, cutp, dtp, SS, out);
}

// Round 12
// 303.422 us; speedup vs baseline: 1.0220x; 1.0220x over previous
//
#include <hip/hip_runtime.h>
#include <math.h>

#define N_NODES 100000
#define N_EDGES 1600000
#define IN_C    128
#define HID     256
#define KEIG    64
#define OUT_C   16

#define NPB      256
#define NBUCKET  ((N_NODES + NPB - 1) / NPB)             // 391
#define EDGE_TILE 4096
#define NTILE    ((N_EDGES + EDGE_TILE - 1) / EDGE_TILE) // 391
#define CAP      8960

#define TRANS_BLOCKS   ((N_NODES + 63) / 64)             // 1563
#define GATHER_BLOCKS  2048
#define CUT_BLOCKS     2048
#define SSP_BLOCKS     512
#define OUTG_BLOCKS    384
// interleaved tail: period 23 = 16 cut + 4 ss + 3 out, x128 groups
#define TAIL_BLOCKS    (128 * 23)                        // 2944

typedef __attribute__((ext_vector_type(8))) short short8;
typedef __attribute__((ext_vector_type(4))) float f32x4;

__device__ __forceinline__ float wave_sum(float v) {
#pragma unroll
    for (int m = 32; m; m >>= 1) v += __shfl_xor(v, m, 64);
    return v;
}
__device__ __forceinline__ float wave_max(float v) {
#pragma unroll
    for (int m = 32; m; m >>= 1) v = fmaxf(v, __shfl_xor(v, m, 64));
    return v;
}
__device__ __forceinline__ float bf2f(unsigned int u) {
    return __uint_as_float((u & 0xffffu) << 16);
}
__device__ __forceinline__ unsigned short f2bf(float f) {
    unsigned int u = __float_as_uint(f);
    u += 0x7fff + ((u >> 16) & 1);
    return (unsigned short)(u >> 16);
}
__device__ __forceinline__ float fp8tof(int b) {
    return __builtin_amdgcn_cvt_f32_fp8(b, 0);
}
__device__ __forceinline__ unsigned char f2fp8(float f) {
    int p = __builtin_amdgcn_cvt_pk_fp8_f32(f, f, 0, false);
    return (unsigned char)(p & 0xff);
}

#define FMA4(P, s, W) \
    P.x = fmaf(s, W.x, P.x); P.y = fmaf(s, W.y, P.y); \
    P.z = fmaf(s, W.z, P.z); P.w = fmaf(s, W.w, P.w);

#define GATHER16(TBL, DST) do {                                               \
    int r0 = csr_row[ps + j + 0],  r1 = csr_row[ps + j + 1];                  \
    int r2 = csr_row[ps + j + 2],  r3 = csr_row[ps + j + 3];                  \
    int r4 = csr_row[ps + j + 4],  r5 = csr_row[ps + j + 5];                  \
    int r6 = csr_row[ps + j + 6],  r7 = csr_row[ps + j + 7];                  \
    int r8 = csr_row[ps + j + 8],  r9 = csr_row[ps + j + 9];                  \
    int rA = csr_row[ps + j + 10], rB = csr_row[ps + j + 11];                 \
    int rC = csr_row[ps + j + 12], rD = csr_row[ps + j + 13];                 \
    int rE = csr_row[ps + j + 14], rF = csr_row[ps + j + 15];                 \
    int b0 = TBL[(unsigned)r0 * 64u + lane], b1 = TBL[(unsigned)r1 * 64u + lane]; \
    int b2 = TBL[(unsigned)r2 * 64u + lane], b3 = TBL[(unsigned)r3 * 64u + lane]; \
    int b4 = TBL[(unsigned)r4 * 64u + lane], b5 = TBL[(unsigned)r5 * 64u + lane]; \
    int b6 = TBL[(unsigned)r6 * 64u + lane], b7 = TBL[(unsigned)r7 * 64u + lane]; \
    int b8 = TBL[(unsigned)r8 * 64u + lane], b9 = TBL[(unsigned)r9 * 64u + lane]; \
    int bA = TBL[(unsigned)rA * 64u + lane], bB = TBL[(unsigned)rB * 64u + lane]; \
    int bC = TBL[(unsigned)rC * 64u + lane], bD = TBL[(unsigned)rD * 64u + lane]; \
    int bE = TBL[(unsigned)rE * 64u + lane], bF = TBL[(unsigned)rF * 64u + lane]; \
    DST += (((fp8tof(b0) + fp8tof(b1)) + (fp8tof(b2) + fp8tof(b3)))           \
          + ((fp8tof(b4) + fp8tof(b5)) + (fp8tof(b6) + fp8tof(b7))))          \
         + (((fp8tof(b8) + fp8tof(b9)) + (fp8tof(bA) + fp8tof(bB)))           \
          + ((fp8tof(bC) + fp8tof(bD)) + (fp8tof(bE) + fp8tof(bF))));         \
} while (0)

// ---------------- small precompute ----------------
__global__ void prep_weff(const float* __restrict__ mlpxW, const float* __restrict__ mlpxb,
                          const float* __restrict__ finW, const float* __restrict__ finb,
                          float* __restrict__ Weff, float* __restrict__ beff,
                          int* __restrict__ bcnt, unsigned char* __restrict__ WT8,
                          unsigned char* __restrict__ S8, int* __restrict__ gpad) {
    int t = blockIdx.x * blockDim.x + threadIdx.x;
    const int NW = (IN_C + KEIG) * OUT_C;
    if (t < NW) {
        int k = t >> 4, o = t & 15;
        float acc;
        if (k < IN_C) {
            acc = 0.f;
            for (int c = 0; c < HID; ++c)
                acc += mlpxW[c * IN_C + k] * finW[o * (HID + KEIG) + c];
        } else {
            acc = finW[o * (HID + KEIG) + HID + (k - IN_C)];
        }
        Weff[k * OUT_C + o] = acc;
    }
    int tb = t - NW;
    if (tb >= 0 && tb < OUT_C) {
        float acc = finb[tb];
        for (int c = 0; c < HID; ++c) acc += mlpxb[c] * finW[tb * (HID + KEIG) + c];
        beff[tb] = acc;
    }
    int tz = t - (NW + OUT_C);
    if (tz >= 0 && tz <= NBUCKET) bcnt[tz] = 0;
    int tp = t - (NW + OUT_C + NBUCKET + 1);
    if (tp >= 0 && tp < 16) {
        ((int*)(WT8 + (size_t)N_NODES * 64))[tp] = 0;
        ((int*)(S8 + (size_t)N_NODES * 64))[tp] = 0;
        if (tp == 0) *gpad = 0;
    }
}

// ---------------- fused: transpose_w | bucket_hist ----------------
__global__ __launch_bounds__(256) void fused_prep(const float* __restrict__ W,
                                                  unsigned char* __restrict__ WT8,
                                                  const int* __restrict__ ei,
                                                  int* __restrict__ bcnt) {
    __shared__ __align__(16) char sm[64 * 65 * 4];
    int t = threadIdx.x;
    if (blockIdx.x < TRANS_BLOCKS) {
        float (*tile)[65] = (float (*)[65])sm;
        int n0 = blockIdx.x * 64;
        int tn = t & 63, tq = t >> 6;
#pragma unroll
        for (int kk = 0; kk < 16; ++kk) {
            int k = tq * 16 + kk;
            int n = n0 + tn;
            tile[k][tn] = (n < N_NODES) ? W[(long long)k * N_NODES + n] : 0.f;
        }
        __syncthreads();
        int tk = t & 63;
#pragma unroll
        for (int ii = 0; ii < 16; ++ii) {
            int n = n0 + tq * 16 + ii;
            if (n < N_NODES) WT8[(unsigned)n * 64u + tk] = f2fp8(tile[tk][tq * 16 + ii] * 32.f);
        }
    } else {
        int* h = (int*)sm;
        for (int i = t; i < NBUCKET; i += 256) h[i] = 0;
        __syncthreads();
        int tile_i = blockIdx.x - TRANS_BLOCKS;
        int e0 = tile_i * EDGE_TILE;
        int e1 = min(e0 + EDGE_TILE, N_EDGES);
        for (int e = e0 + t; e < e1; e += 256)
            atomicAdd(&h[ei[N_EDGES + e] >> 8], 1);
        __syncthreads();
        for (int i = t; i < NBUCKET; i += 256)
            if (h[i]) atomicAdd(&bcnt[i], h[i]);
    }
}

__global__ void bucket_scan(const int* __restrict__ bcnt, int* __restrict__ bbase,
                            int* __restrict__ bcur) {
    __shared__ int sh[512];
    int t = threadIdx.x;
    int v = (t < NBUCKET) ? bcnt[t] : 0;
    sh[t] = v;
    __syncthreads();
    for (int d = 1; d < 512; d <<= 1) {
        int u = (t >= d) ? sh[t - d] : 0;
        __syncthreads();
        sh[t] += u;
        __syncthreads();
    }
    if (t < NBUCKET) { bbase[t] = sh[t] - v; bcur[t] = sh[t] - v; }
    if (t == 0) bbase[NBUCKET] = N_EDGES;
}

__global__ void bucket_scatter(const int* __restrict__ ei, int* __restrict__ bcur,
                               int* __restrict__ ebuf) {
    __shared__ int h[NBUCKET];
    __shared__ int gb[NBUCKET];
    __shared__ int lpre[NBUCKET];
    __shared__ int psum[256];
    __shared__ int stage[EDGE_TILE];
    __shared__ short bkt[EDGE_TILE];
    int t = threadIdx.x;
    for (int i = t; i < NBUCKET; i += 256) h[i] = 0;
    __syncthreads();
    int e0 = blockIdx.x * EDGE_TILE;
    int e1 = min(e0 + EDGE_TILE, N_EDGES);
    int nt = e1 - e0;
    for (int e = e0 + t; e < e1; e += 256)
        atomicAdd(&h[ei[N_EDGES + e] >> 8], 1);
    __syncthreads();
    int a0 = (2 * t < NBUCKET) ? h[2 * t] : 0;
    int a1 = (2 * t + 1 < NBUCKET) ? h[2 * t + 1] : 0;
    psum[t] = a0 + a1;
    __syncthreads();
    for (int d = 1; d < 256; d <<= 1) {
        int u = (t >= d) ? psum[t - d] : 0;
        __syncthreads();
        psum[t] += u;
        __syncthreads();
    }
    int base = (t == 0) ? 0 : psum[t - 1];
    if (2 * t < NBUCKET) lpre[2 * t] = base;
    if (2 * t + 1 < NBUCKET) lpre[2 * t + 1] = base + a0;
    __syncthreads();
    for (int i = t; i < NBUCKET; i += 256) {
        int c = h[i];
        gb[i] = c ? atomicAdd(&bcur[i], c) : 0;
        h[i] = lpre[i];
    }
    __syncthreads();
    for (int e = e0 + t; e < e1; e += 256) {
        int r = ei[e];
        int c = ei[N_EDGES + e];
        int b = c >> 8;
        int slot = atomicAdd(&h[b], 1);
        stage[slot] = r | ((c & 255) << 17);
        bkt[slot] = (short)b;
    }
    __syncthreads();
    for (int s = t; s < nt; s += 256) {
        int b = bkt[s];
        ebuf[gb[b] + s - lpre[b]] = stage[s];
    }
}

__global__ void csr_build(const int* __restrict__ ebuf, const int* __restrict__ bbase,
                          int* __restrict__ offsets, int* __restrict__ pstart,
                          int* __restrict__ csr_row, int* __restrict__ gpad) {
    __shared__ int hist[NPB];
    __shared__ int sh[NPB];
    __shared__ int curs[NPB];
    __shared__ int staged[CAP];
    __shared__ int pbase_sh;
    int b = blockIdx.x;
    int t = threadIdx.x;
    int s0 = bbase[b], s1 = bbase[b + 1];
    hist[t] = 0;
    __syncthreads();
    for (int i = s0 + t; i < s1; i += 256)
        atomicAdd(&hist[ebuf[i] >> 17], 1);
    __syncthreads();
    int v = hist[t];
    int pv = (v + 15) & ~15;
    sh[t] = pv;
    __syncthreads();
    for (int d = 1; d < 256; d <<= 1) {
        int u = (t >= d) ? sh[t - d] : 0;
        __syncthreads();
        sh[t] += u;
        __syncthreads();
    }
    int pexcl = sh[t] - pv;
    int pt = sh[255];
    if (t == 0) pbase_sh = atomicAdd(gpad, pt);
    __syncthreads();
    int pbase = pbase_sh;
    int node = b * NPB + t;
    if (node < N_NODES) { offsets[node] = v; pstart[node] = pbase + pexcl; }
    curs[t] = pexcl;
    __syncthreads();
    if (pt <= CAP) {
        for (int i = t; i < pt; i += 256) staged[i] = N_NODES;
        __syncthreads();
        for (int i = s0 + t; i < s1; i += 256) {
            int pk = ebuf[i];
            int pos = atomicAdd(&curs[pk >> 17], 1);
            staged[pos] = pk & 0x1FFFF;
        }
        __syncthreads();
        for (int i = t; i < pt; i += 256) csr_row[pbase + i] = staged[i];
    } else {
        for (int i = t; i < pt; i += 256) csr_row[pbase + i] = N_NODES;
        __syncthreads();
        for (int i = s0 + t; i < s1; i += 256) {
            int pk = ebuf[i];
            int pos = atomicAdd(&curs[pk >> 17], 1);
            csr_row[pbase + pos] = pk & 0x1FFFF;
        }
    }
}

// ---------------- pass 1: padded 16-wide fp8 gather + softmax + deg_term ---------
__global__ void gather_softmax(const int* __restrict__ offsets, const int* __restrict__ pstart,
                               const int* __restrict__ csr_row,
                               const unsigned char* __restrict__ WT8,
                               const float* __restrict__ MLPb,
                               unsigned short* __restrict__ Sb,
                               unsigned char* __restrict__ S8,
                               float* __restrict__ dtp) {
    int lane = threadIdx.x & 63;
    int wib = __builtin_amdgcn_readfirstlane(threadIdx.x >> 6);
    int gw = blockIdx.x * 4 + wib;
    int nw = gridDim.x * 4;
    float bias = MLPb[lane];
    float dacc = 0.f;
    for (int n = gw; n < N_NODES; n += nw) {
        int deg = __builtin_amdgcn_readfirstlane(offsets[n]);
        int ps  = __builtin_amdgcn_readfirstlane(pstart[n]);
        int plen = (deg + 15) & ~15;
        float acc = 0.f;
        for (int j = 0; j < plen; j += 16) GATHER16(WT8, acc);
        acc = bias + acc * 0.03125f;
        float m = wave_max(acc);
        float e = __expf(acc - m);
        float sm = wave_sum(e);
        float sv = e / sm;
        unsigned idx = (unsigned)n * 64u + lane;
        Sb[idx] = f2bf(sv);
        S8[idx] = f2fp8(sv * 64.f);
        dacc += (float)deg * sv * sv;
    }
    dacc = wave_sum(dacc);
    __shared__ float red[4];
    if (lane == 0) red[wib] = dacc;
    __syncthreads();
    if (threadIdx.x == 0) dtp[blockIdx.x] = red[0] + red[1] + red[2] + red[3];
}

// ---------------- fused tail, role-interleaved: 16 cut | 4 ss | 3 out per 23 ----
__global__ __launch_bounds__(256) void fused_tail(
        const int* __restrict__ offsets, const int* __restrict__ pstart,
        const int* __restrict__ csr_row,
        const unsigned short* __restrict__ Sb, const unsigned char* __restrict__ S8,
        float* __restrict__ cutp, float* __restrict__ ssp,
        const float* __restrict__ x, const float* __restrict__ Weff,
        const float* __restrict__ beff, float* __restrict__ out) {
    __shared__ __align__(16) char sm[768 * 16 + 64];
    int t = threadIdx.x;
    int grp = blockIdx.x / 23;
    int r23 = blockIdx.x % 23;

    if (r23 < 16) {
        // ---- cut ----
        int bid = grp * 16 + r23;                 // 0..2047
        int lane = t & 63;
        int wib = __builtin_amdgcn_readfirstlane(t >> 6);
        int gw = bid * 4 + wib;
        int nw = CUT_BLOCKS * 4;
        float acc = 0.f;
        for (int n = gw; n < N_NODES; n += nw) {
            float sc = bf2f(Sb[(unsigned)n * 64u + lane]);
            int deg = __builtin_amdgcn_readfirstlane(offsets[n]);
            int ps  = __builtin_amdgcn_readfirstlane(pstart[n]);
            int plen = (deg + 15) & ~15;
            float g = 0.f;
            for (int j = 0; j < plen; j += 16) GATHER16(S8, g);
            acc += sc * g * 0.015625f;
        }
        acc = wave_sum(acc);
        float* red = (float*)sm;
        if (lane == 0) red[wib] = acc;
        __syncthreads();
        if (t == 0) cutp[bid] = red[0] + red[1] + red[2] + red[3];
    } else if (r23 < 20) {
        // ---- SS = S^T S via MFMA ----
        int bid2 = grp * 4 + (r23 - 16);          // 0..511
        unsigned short (*Sr)[66] = (unsigned short (*)[66])sm;
        int lane = t & 63;
        int w = t >> 6;
        int m = lane & 15;
        int quad = lane >> 4;
        int srow = t >> 3;
        int spart = t & 7;
        f32x4 a0 = {0.f,0.f,0.f,0.f}, a1 = {0.f,0.f,0.f,0.f};
        f32x4 a2 = {0.f,0.f,0.f,0.f}, a3 = {0.f,0.f,0.f,0.f};
        for (int base = bid2 * 32; base < N_NODES; base += SSP_BLOCKS * 32) {
            const uint4* g = (const uint4*)(Sb + (long long)(base + srow) * 64 + spart * 8);
            uint4 d = *g;
            __syncthreads();
            unsigned int* rowp = (unsigned int*)&Sr[srow][0];
            rowp[spart * 4 + 0] = d.x;
            rowp[spart * 4 + 1] = d.y;
            rowp[spart * 4 + 2] = d.z;
            rowp[spart * 4 + 3] = d.w;
            __syncthreads();
            short8 f0, f1, f2, f3;
#pragma unroll
            for (int j = 0; j < 8; ++j) {
                int k = quad * 8 + j;
                f0[j] = (short)Sr[k][m];
                f1[j] = (short)Sr[k][16 + m];
                f2[j] = (short)Sr[k][32 + m];
                f3[j] = (short)Sr[k][48 + m];
            }
            short8 fa = (w == 0) ? f0 : (w == 1) ? f1 : (w == 2) ? f2 : f3;
            a0 = __builtin_amdgcn_mfma_f32_16x16x32_bf16(fa, f0, a0, 0, 0, 0);
            a1 = __builtin_amdgcn_mfma_f32_16x16x32_bf16(fa, f1, a1, 0, 0, 0);
            a2 = __builtin_amdgcn_mfma_f32_16x16x32_bf16(fa, f2, a2, 0, 0, 0);
            a3 = __builtin_amdgcn_mfma_f32_16x16x32_bf16(fa, f3, a3, 0, 0, 0);
        }
        float* dst = ssp + (size_t)bid2 * 4096;
#pragma unroll
        for (int r = 0; r < 4; ++r) {
            int row = w * 16 + quad * 4 + r;
            dst[row * 64 +  0 + m] = a0[r];
            dst[row * 64 + 16 + m] = a1[r];
            dst[row * 64 + 32 + m] = a2[r];
            dst[row * 64 + 48 + m] = a3[r];
        }
    } else {
        // ---- out: logits + log_softmax (grid-stride over rows) ----
        int obid = grp * 3 + (r23 - 20);          // 0..383
        float4* Wsh = (float4*)sm;
        float* bsh = (float*)(sm + 768 * 16);
        const float4* W4 = (const float4*)Weff;
        for (int i = t; i < 768; i += 256) Wsh[i] = W4[i];
        if (t < 16) bsh[t] = beff[t];
        __syncthreads();
        for (int r = obid * 256 + t; r < N_NODES; r += OUTG_BLOCKS * 256) {
            float4 p0 = make_float4(bsh[0], bsh[1], bsh[2], bsh[3]);
            float4 p1 = make_float4(bsh[4], bsh[5], bsh[6], bsh[7]);
            float4 p2 = make_float4(bsh[8], bsh[9], bsh[10], bsh[11]);
            float4 p3 = make_float4(bsh[12], bsh[13], bsh[14], bsh[15]);
            const float4* xr = (const float4*)(x + (long long)r * IN_C);
#pragma unroll 8
            for (int j = 0; j < 32; ++j) {
                float4 xv = xr[j];
                int k = j * 4;
                float xs[4] = {xv.x, xv.y, xv.z, xv.w};
#pragma unroll
                for (int c = 0; c < 4; ++c) {
                    float s = xs[c];
                    float4 w0 = Wsh[(k + c) * 4 + 0];
                    float4 w1 = Wsh[(k + c) * 4 + 1];
                    float4 w2 = Wsh[(k + c) * 4 + 2];
                    float4 w3 = Wsh[(k + c) * 4 + 3];
                    FMA4(p0, s, w0); FMA4(p1, s, w1); FMA4(p2, s, w2); FMA4(p3, s, w3);
                }
            }
            const uint2* sr = (const uint2*)(Sb + (long long)r * 64);
#pragma unroll 8
            for (int j = 0; j < 16; ++j) {
                uint2 u = sr[j];
                float xs[4] = {bf2f(u.x), bf2f(u.x >> 16), bf2f(u.y), bf2f(u.y >> 16)};
                int k = IN_C + j * 4;
#pragma unroll
                for (int c = 0; c < 4; ++c) {
                    float s = xs[c];
                    float4 w0 = Wsh[(k + c) * 4 + 0];
                    float4 w1 = Wsh[(k + c) * 4 + 1];
                    float4 w2 = Wsh[(k + c) * 4 + 2];
                    float4 w3 = Wsh[(k + c) * 4 + 3];
                    FMA4(p0, s, w0); FMA4(p1, s, w1); FMA4(p2, s, w2); FMA4(p3, s, w3);
                }
            }
            float m = fmaxf(fmaxf(fmaxf(p0.x, p0.y), fmaxf(p0.z, p0.w)),
                            fmaxf(fmaxf(fmaxf(p1.x, p1.y), fmaxf(p1.z, p1.w)),
                                  fmaxf(fmaxf(fmaxf(p2.x, p2.y), fmaxf(p2.z, p2.w)),
                                        fmaxf(fmaxf(p3.x, p3.y), fmaxf(p3.z, p3.w)))));
            float sum = __expf(p0.x - m) + __expf(p0.y - m) + __expf(p0.z - m) + __expf(p0.w - m)
                      + __expf(p1.x - m) + __expf(p1.y - m) + __expf(p1.z - m) + __expf(p1.w - m)
                      + __expf(p2.x - m) + __expf(p2.y - m) + __expf(p2.z - m) + __expf(p2.w - m)
                      + __expf(p3.x - m) + __expf(p3.y - m) + __expf(p3.z - m) + __expf(p3.w - m);
            float lse = m + logf(sum);
            float4* o4 = (float4*)(out + (long long)r * OUT_C);
            o4[0] = make_float4(p0.x - lse, p0.y - lse, p0.z - lse, p0.w - lse);
            o4[1] = make_float4(p1.x - lse, p1.y - lse, p1.z - lse, p1.w - lse);
            o4[2] = make_float4(p2.x - lse, p2.y - lse, p2.z - lse, p2.w - lse);
            o4[3] = make_float4(p3.x - lse, p3.y - lse, p3.z - lse, p3.w - lse);
        }
    }
}

__global__ void reduce_ss(const float* __restrict__ ssp, float* __restrict__ SS) {
    int e = blockIdx.x * blockDim.x + threadIdx.x;
    float s = 0.f;
    for (int p = 0; p < SSP_BLOCKS; ++p) s += ssp[(size_t)p * 4096 + e];
    SS[e] = s;
}

// ---------------- scalar losses ----------------
__global__ void scalars_kernel(const float* __restrict__ cutp, const float* __restrict__ dtp,
                               const float* __restrict__ SS, float* __restrict__ out) {
    __shared__ float red[256];
    int t = threadIdx.x;
    float c = 0.f;
    for (int i = t; i < CUT_BLOCKS; i += 256) c += cutp[i];
    red[t] = c; __syncthreads();
    for (int s = 128; s; s >>= 1) { if (t < s) red[t] += red[t + s]; __syncthreads(); }
    float cut = red[0]; __syncthreads();

    float d = 0.f;
    for (int i = t; i < GATHER_BLOCKS; i += 256) d += dtp[i];
    red[t] = d; __syncthreads();
    for (int s = 128; s; s >>= 1) { if (t < s) red[t] += red[t + s]; __syncthreads(); }
    float dterm = red[0]; __syncthreads();

    float ss[16];
    float sq = 0.f;
#pragma unroll
    for (int j = 0; j < 16; ++j) { ss[j] = SS[t * 16 + j]; sq += ss[j] * ss[j]; }
    red[t] = sq; __syncthreads();
    for (int s = 128; s; s >>= 1) { if (t < s) red[t] += red[t + s]; __syncthreads(); }
    float nrm = sqrtf(red[0]); __syncthreads();

    float osq = 0.f;
#pragma unroll
    for (int j = 0; j < 16; ++j) {
        int idx = t * 16 + j;
        float v = ss[j] / nrm - ((idx % 65 == 0) ? 0.125f : 0.f);
        osq += v * v;
    }
    red[t] = osq; __syncthreads();
    for (int s = 128; s; s >>= 1) { if (t < s) red[t] += red[t + s]; __syncthreads(); }
    if (t == 0) {
        float loss = -(cut / dterm) + sqrtf(red[0]);
        out[(long long)N_NODES * OUT_C] = loss;
    }
}

extern "C" void kernel_launch(void* const* d_in, const int* in_sizes, int n_in,
                              void* d_out, int out_size, void* d_ws, size_t ws_size,
                              hipStream_t stream) {
    const float* x     = (const float*)d_in[0];
    const int*   ei    = (const int*)d_in[1];
    const float* MLPW  = (const float*)d_in[2];
    const float* MLPb  = (const float*)d_in[3];
    const float* mlpxW = (const float*)d_in[4];
    const float* mlpxb = (const float*)d_in[5];
    const float* finW  = (const float*)d_in[6];
    const float* finb  = (const float*)d_in[7];
    float* out = (float*)d_out;
    char* ws = (char*)d_ws;

    unsigned char*  WT8 = (unsigned char*)ws;                                 // (N+1)*64
    unsigned char*  S8  = (unsigned char*)(ws + (size_t)(N_NODES + 1) * 64);  // (N+1)*64
    unsigned short* Sb  = (unsigned short*)(ws + (size_t)(N_NODES + 1) * 128);// N*64*2
    char* p = ws + (size_t)(N_NODES + 1) * 128 + (size_t)N_NODES * 128;
    float* ssp  = (float*)p;                                 // 512*4096 f
    float* SS   = ssp + (size_t)SSP_BLOCKS * 4096;           // 4096
    float* Weff = SS + 4096;                                 // 3072
    float* beff = Weff + 192 * 16;                           // 16
    float* cutp = beff + 16;                                 // CUT_BLOCKS
    float* dtp  = cutp + CUT_BLOCKS;                         // GATHER_BLOCKS
    int* ebuf    = (int*)(dtp + GATHER_BLOCKS);              // E
    int* csr_row = ebuf + N_EDGES;                           // E + 16N (padded)
    int* offsets = csr_row + N_EDGES + 16 * N_NODES;         // N+1
    int* pstart  = offsets + N_NODES + 1;                    // N
    int* bcnt    = pstart + N_NODES;                         // NBUCKET+1
    int* bbase   = bcnt + NBUCKET + 1;                       // NBUCKET+1
    int* bcur    = bbase + NBUCKET + 1;                      // NBUCKET
    int* gpad    = bcur + NBUCKET;                           // 1

    hipLaunchKernelGGL(prep_weff, dim3(16), dim3(256), 0, stream,
                       mlpxW, mlpxb, finW, finb, Weff, beff, bcnt, WT8, S8, gpad);
    hipLaunchKernelGGL(fused_prep, dim3(TRANS_BLOCKS + NTILE), dim3(256), 0, stream,
                       MLPW, WT8, ei, bcnt);
    hipLaunchKernelGGL(bucket_scan, dim3(1), dim3(512), 0, stream, bcnt, bbase, bcur);
    hipLaunchKernelGGL(bucket_scatter, dim3(NTILE), dim3(256), 0, stream, ei, bcur, ebuf);
    hipLaunchKernelGGL(csr_build, dim3(NBUCKET), dim3(256), 0, stream,
                       ebuf, bbase, offsets, pstart, csr_row, gpad);
    hipLaunchKernelGGL(gather_softmax, dim3(GATHER_BLOCKS), dim3(256), 0, stream,
                       offsets, pstart, csr_row, WT8, MLPb, Sb, S8, dtp);
    hipLaunchKernelGGL(fused_tail, dim3(TAIL_BLOCKS), dim3(256), 0, stream,
                       offsets, pstart, csr_row, Sb, S8, cutp, ssp, x, Weff, beff, out);
    hipLaunchKernelGGL(reduce_ss, dim3(16), dim3(256), 0, stream, ssp, SS);
    hipLaunchKernelGGL(scalars_kernel, dim3(1), dim3(256), 0, stream, cutp, dtp, SS, out);
}